// Round 1
// 696.088 us; speedup vs baseline: 1.0075x; 1.0075x over previous
//
#include <hip/hip_runtime.h>
#include <math.h>

#define N_ROWS 1048576
#define H 128
#define B 128
#define NEG_SLOPE 0.01f

#define GRID_MAIN 2048
#define ROWS_PB (N_ROWS / GRID_MAIN)      // 512 rows per block
#define MAXP 256                          // partial slots per segment

__device__ __forceinline__ float dot4(float4 a, float4 b) {
    return a.x * b.x + a.y * b.y + a.z * b.z + a.w * b.w;
}

// ---------- qs = aq @ w_q (one dot per segment) + zero the slot counters ----------
__global__ __launch_bounds__(256) void qs_init_kernel(const float* __restrict__ aq,
                                                      const float* __restrict__ w,
                                                      float* __restrict__ qs,
                                                      int* __restrict__ counter) {
    if (blockIdx.x == 0 && threadIdx.x < B) counter[threadIdx.x] = 0;
    const int lane = threadIdx.x & 63;
    const int wave = threadIdx.x >> 6;
    const int half = lane >> 5;
    const int hl   = lane & 31;
    const int b    = blockIdx.x * 8 + wave * 2 + half;   // grid 16 x 256 -> 128
    float4 w4 = ((const float4*)(w + H))[hl];
    float4 a4 = ((const float4*)(aq + (long)b * H))[hl];
    float d = dot4(a4, w4);
    #pragma unroll
    for (int off = 1; off < 32; off <<= 1) d += __shfl_xor(d, off, 32);
    if (hl == 0) qs[b] = d;
}

// ---------- single pass: gate + online softmax + partial flush ----------
__global__ __launch_bounds__(256) void main_kernel(const float* __restrict__ h,
                                                   const int* __restrict__ seg,
                                                   const float* __restrict__ w,
                                                   const float* __restrict__ qs,
                                                   int* __restrict__ counter,
                                                   float* __restrict__ pm,
                                                   float* __restrict__ pd,
                                                   float* __restrict__ pacc) {
    __shared__ float qs_s[B];
    __shared__ float sm[4];                              // per-wave running max
    __shared__ float sd[4];                              // per-wave denom
    __shared__ float sacc[4][H];                         // per-wave acc (2 KB)
    if (threadIdx.x < B) qs_s[threadIdx.x] = qs[threadIdx.x];
    __syncthreads();

    const int lane = threadIdx.x & 63;
    const int wave = threadIdx.x >> 6;
    const int half = lane >> 5;
    const int hl   = lane & 31;
    const int hwid = wave * 2 + half;                    // 0..7
    const long r0  = (long)blockIdx.x * ROWS_PB;

    float4 w4 = ((const float4*)w)[hl];                  // w_h fragment

    const int sFirst = seg[r0];
    const int sLast  = seg[r0 + ROWS_PB - 1];

    if (sFirst == sLast) {
        // ---------------- FAST PATH: whole block in one segment ----------------
        const float qsv = qs_s[sFirst];
        float  m_run = -1e30f;
        float  d_run = 0.0f;
        float4 acc   = {0.0f, 0.0f, 0.0f, 0.0f};

        for (int it = 0; it < ROWS_PB / 32; ++it) {      // 16 iters, 4 consecutive rows/half-wave
            long base = r0 + (long)it * 32 + hwid * 4;
            const float4* hp = (const float4*)(h + base * H) + hl;
            float4 h0 = hp[0];                           // row base   (128 f = 32 float4)
            float4 h1 = hp[32];                          // row base+1
            float4 h2 = hp[64];                          // row base+2
            float4 h3 = hp[96];                          // row base+3

            float d0 = dot4(h0, w4), d1 = dot4(h1, w4);
            float d2 = dot4(h2, w4), d3 = dot4(h3, w4);

            // packed butterfly: 13 shuffles for 4 row-sums + broadcast (vs 20)
            float s0 = d0 + __shfl_xor(d0, 16, 32);
            float s1 = d1 + __shfl_xor(d1, 16, 32);
            float s2 = d2 + __shfl_xor(d2, 16, 32);
            float s3 = d3 + __shfl_xor(d3, 16, 32);
            float z01 = (hl & 16) ? s1 : s0;             // rows 0|1 in lane halves
            float z23 = (hl & 16) ? s3 : s2;             // rows 2|3
            float t01 = z01 + __shfl_xor(z01, 8, 32);
            float t23 = z23 + __shfl_xor(z23, 8, 32);
            float zz  = (hl & 8) ? t23 : t01;            // rows 0,2,1,3 in 8-lane groups
            zz += __shfl_xor(zz, 4, 32);
            zz += __shfl_xor(zz, 2, 32);
            zz += __shfl_xor(zz, 1, 32);
            float g0 = __shfl(zz,  0, 32) + qsv;
            float g1 = __shfl(zz, 16, 32) + qsv;
            float g2 = __shfl(zz,  8, 32) + qsv;
            float g3 = __shfl(zz, 24, 32) + qsv;
            g0 = (g0 >= 0.0f) ? g0 : NEG_SLOPE * g0;
            g1 = (g1 >= 0.0f) ? g1 : NEG_SLOPE * g1;
            g2 = (g2 >= 0.0f) ? g2 : NEG_SLOPE * g2;
            g3 = (g3 >= 0.0f) ? g3 : NEG_SLOPE * g3;

            // branchless batched online update: depth = 1 exp + fma tree
            // (old code: 4 sequential exp->5FMA chains + divergent rare path)
            float M  = fmaxf(fmaxf(m_run, g0), fmaxf(fmaxf(g1, g2), g3));
            float sc = __expf(m_run - M);                // == 1.0 when no new max; 0 on first iter
            float e0 = __expf(g0 - M);
            float e1 = __expf(g1 - M);
            float e2 = __expf(g2 - M);
            float e3 = __expf(g3 - M);
            acc.x = fmaf(acc.x, sc, fmaf(e0, h0.x, e1 * h1.x) + fmaf(e2, h2.x, e3 * h3.x));
            acc.y = fmaf(acc.y, sc, fmaf(e0, h0.y, e1 * h1.y) + fmaf(e2, h2.y, e3 * h3.y));
            acc.z = fmaf(acc.z, sc, fmaf(e0, h0.z, e1 * h1.z) + fmaf(e2, h2.z, e3 * h3.z));
            acc.w = fmaf(acc.w, sc, fmaf(e0, h0.w, e1 * h1.w) + fmaf(e2, h2.w, e3 * h3.w));
            d_run = fmaf(d_run, sc, (e0 + e1) + (e2 + e3));
            m_run = M;
        }
        // cross-half merge -> one partial per wave
        float m_o = __shfl_xor(m_run, 32);
        float d_o = __shfl_xor(d_run, 32);
        float4 a_o;
        a_o.x = __shfl_xor(acc.x, 32);
        a_o.y = __shfl_xor(acc.y, 32);
        a_o.z = __shfl_xor(acc.z, 32);
        a_o.w = __shfl_xor(acc.w, 32);
        float M  = fmaxf(m_run, m_o);
        float ss = __expf(m_run - M);
        float so = __expf(m_o  - M);
        float4 am;
        am.x = acc.x * ss + a_o.x * so;
        am.y = acc.y * ss + a_o.y * so;
        am.z = acc.z * ss + a_o.z * so;
        am.w = acc.w * ss + a_o.w * so;
        float Dm = d_run * ss + d_o * so;

        // cross-wave merge via LDS -> ONE partial per block (was 4)
        if (half == 0) ((float4*)&sacc[wave][0])[hl] = am;
        if (lane == 0) { sm[wave] = M; sd[wave] = Dm; }
        __syncthreads();
        if (wave == 0) {
            float Mb = fmaxf(fmaxf(sm[0], sm[1]), fmaxf(sm[2], sm[3]));
            float e0 = __expf(sm[0] - Mb);
            float e1 = __expf(sm[1] - Mb);
            float e2 = __expf(sm[2] - Mb);
            float e3 = __expf(sm[3] - Mb);
            // lane j owns columns 2j, 2j+1 (2-way LDS aliasing = free)
            int c = lane * 2;
            float2 a;
            a.x = fmaf(e0, sacc[0][c],     e1 * sacc[1][c])     + fmaf(e2, sacc[2][c],     e3 * sacc[3][c]);
            a.y = fmaf(e0, sacc[0][c + 1], e1 * sacc[1][c + 1]) + fmaf(e2, sacc[2][c + 1], e3 * sacc[3][c + 1]);
            float Db = fmaf(e0, sd[0], e1 * sd[1]) + fmaf(e2, sd[2], e3 * sd[3]);

            int slot = 0;
            if (lane == 0) slot = atomicAdd(counter + sFirst, 1);
            slot = min(__shfl(slot, 0), MAXP - 1);
            long pbase = (long)sFirst * MAXP + slot;
            ((float2*)(pacc + pbase * H))[lane] = a;
            if (lane == 0) { pm[pbase] = Mb; pd[pbase] = Db; }
        }
    } else {
        // ---------------- SLOW PATH: block crosses segment boundary ----------------
        int    cur   = -1;
        float  m_run = -1e30f;
        float  d_run = 0.0f;
        float4 acc   = {0.0f, 0.0f, 0.0f, 0.0f};

        for (int it = 0; it < ROWS_PB / 16; ++it) {      // 32 iters, 2 rows/half-wave
            long r1 = r0 + hwid + (long)it * 16;
            long r2 = r1 + 8;
            float4 ha = ((const float4*)(h + r1 * H))[hl];
            float4 hb = ((const float4*)(h + r2 * H))[hl];
            int s1 = seg[r1];
            int s2 = seg[r2];

            #pragma unroll
            for (int k = 0; k < 2; ++k) {
                float4 h4 = k ? hb : ha;
                int    s  = k ? s2 : s1;
                float d = dot4(h4, w4);
                #pragma unroll
                for (int off = 1; off < 32; off <<= 1) d += __shfl_xor(d, off, 32);
                float g = d + qs_s[s];
                g = (g >= 0.0f) ? g : NEG_SLOPE * g;

                if (s != cur) {                          // half-wave-uniform branch
                    if (cur >= 0) {
                        int slot = 0;
                        if (hl == 0) slot = atomicAdd(counter + cur, 1);
                        slot = min(__shfl(slot, 0, 32), MAXP - 1);
                        long pbase = (long)cur * MAXP + slot;
                        ((float4*)(pacc + pbase * H))[hl] = acc;
                        if (hl == 0) { pm[pbase] = m_run; pd[pbase] = d_run; }
                    }
                    cur = s;
                    m_run = -1e30f;
                    d_run = 0.0f;
                    acc = make_float4(0.0f, 0.0f, 0.0f, 0.0f);
                }
                if (g <= m_run) {
                    float e = __expf(g - m_run);
                    acc.x += e * h4.x;
                    acc.y += e * h4.y;
                    acc.z += e * h4.z;
                    acc.w += e * h4.w;
                    d_run += e;
                } else {
                    float sc = __expf(m_run - g);
                    acc.x = acc.x * sc + h4.x;
                    acc.y = acc.y * sc + h4.y;
                    acc.z = acc.z * sc + h4.z;
                    acc.w = acc.w * sc + h4.w;
                    d_run = d_run * sc + 1.0f;
                    m_run = g;
                }
            }
        }
        if (cur >= 0) {
            int slot = 0;
            if (hl == 0) slot = atomicAdd(counter + cur, 1);
            slot = min(__shfl(slot, 0, 32), MAXP - 1);
            long pbase = (long)cur * MAXP + slot;
            ((float4*)(pacc + pbase * H))[hl] = acc;
            if (hl == 0) { pm[pbase] = m_run; pd[pbase] = d_run; }
        }
    }
}

// ---------- merge partials per segment (parallelized), divide, write out ----------
__global__ __launch_bounds__(128) void merge_kernel(const int* __restrict__ counter,
                                                    const float* __restrict__ pm,
                                                    const float* __restrict__ pd,
                                                    const float* __restrict__ pacc,
                                                    float* __restrict__ out) {
    const int s = blockIdx.x;
    const int t = threadIdx.x;                           // 0..127 = H column
    const int c = min(counter[s], MAXP);
    const long sb = (long)s * MAXP;

    __shared__ float red[2];
    __shared__ float scv[MAXP];

    // phase 1: segment max over partials
    float lm = -1e30f;
    for (int j = t; j < c; j += 128) lm = fmaxf(lm, pm[sb + j]);
    #pragma unroll
    for (int off = 1; off < 64; off <<= 1) lm = fmaxf(lm, __shfl_xor(lm, off));
    if ((t & 63) == 0) red[t >> 6] = lm;
    __syncthreads();
    float M = fmaxf(red[0], red[1]);
    __syncthreads();

    // phase 2a: scales to LDS + denom reduce
    float ld = 0.0f;
    for (int j = t; j < c; j += 128) {
        float sc = __expf(pm[sb + j] - M);
        scv[j] = sc;
        ld += pd[sb + j] * sc;
    }
    #pragma unroll
    for (int off = 1; off < 64; off <<= 1) ld += __shfl_xor(ld, off);
    if ((t & 63) == 0) red[t >> 6] = ld;
    __syncthreads();
    float D = red[0] + red[1];

    // phase 2b: weighted accumulation (coalesced)
    float a = 0.0f;
    #pragma unroll 4
    for (int j = 0; j < c; ++j) a += pacc[(sb + j) * H + t] * scv[j];

    out[s * H + t] = (c > 0) ? a / fmaxf(D, 1e-20f) : 0.0f;
}

extern "C" void kernel_launch(void* const* d_in, const int* in_sizes, int n_in,
                              void* d_out, int out_size, void* d_ws, size_t ws_size,
                              hipStream_t stream) {
    const float* h   = (const float*)d_in[0];   // (N, H)
    const float* aq  = (const float*)d_in[1];   // (B, H)
    const float* w   = (const float*)d_in[2];   // (2H,)
    const int*   seg = (const int*)d_in[3];     // (N,) sorted
    float* out = (float*)d_out;                 // (B, H)

    // ws layout (floats): qs[B] | counter[B] (int) | pm[B*MAXP] | pd[B*MAXP] | pacc[B*MAXP*H]
    float* ws      = (float*)d_ws;
    float* qs      = ws;
    int*   counter = (int*)(ws + B);
    float* pm      = ws + 2 * B;
    float* pd      = ws + 2 * B + B * MAXP;
    float* pacc    = ws + 2 * B + 2 * B * MAXP;   // 16B-aligned

    qs_init_kernel<<<16, 256, 0, stream>>>(aq, w, qs, counter);
    main_kernel<<<GRID_MAIN, 256, 0, stream>>>(h, seg, w, qs, counter, pm, pd, pacc);
    merge_kernel<<<B, 128, 0, stream>>>(counter, pm, pd, pacc, out);
}

// Round 2
// 664.412 us; speedup vs baseline: 1.0555x; 1.0477x over previous
//
#include <hip/hip_runtime.h>
#include <math.h>

#define N_ROWS 1048576
#define H 128
#define B 128
#define NEG_SLOPE 0.01f

#define GRID_MAIN 4096
#define ROWS_PB (N_ROWS / GRID_MAIN)      // 256 rows per block (16 blocks/CU: shorter straggler tail)
#define MAXP 256                          // partial slots per segment

__device__ __forceinline__ float dot4(float4 a, float4 b) {
    return a.x * b.x + a.y * b.y + a.z * b.z + a.w * b.w;
}

typedef float v4f __attribute__((ext_vector_type(4)));
__device__ __forceinline__ float4 ldnt(const float4* p) {
    v4f t = __builtin_nontemporal_load((const v4f*)p);   // h is streamed exactly once: evict-first
    return make_float4(t.x, t.y, t.z, t.w);
}

// ---------- qs = aq @ w_q (one dot per segment) + zero the slot counters ----------
__global__ __launch_bounds__(256) void qs_init_kernel(const float* __restrict__ aq,
                                                      const float* __restrict__ w,
                                                      float* __restrict__ qs,
                                                      int* __restrict__ counter) {
    if (blockIdx.x == 0 && threadIdx.x < B) counter[threadIdx.x] = 0;
    const int lane = threadIdx.x & 63;
    const int wave = threadIdx.x >> 6;
    const int half = lane >> 5;
    const int hl   = lane & 31;
    const int b    = blockIdx.x * 8 + wave * 2 + half;   // grid 16 x 256 -> 128
    float4 w4 = ((const float4*)(w + H))[hl];
    float4 a4 = ((const float4*)(aq + (long)b * H))[hl];
    float d = dot4(a4, w4);
    #pragma unroll
    for (int off = 1; off < 32; off <<= 1) d += __shfl_xor(d, off, 32);
    if (hl == 0) qs[b] = d;
}

// ---------- single pass: gate + online softmax + partial flush ----------
__global__ __launch_bounds__(256) void main_kernel(const float* __restrict__ h,
                                                   const int* __restrict__ seg,
                                                   const float* __restrict__ w,
                                                   const float* __restrict__ qs,
                                                   int* __restrict__ counter,
                                                   float* __restrict__ pm,
                                                   float* __restrict__ pd,
                                                   float* __restrict__ pacc) {
    __shared__ float qs_s[B];
    __shared__ float sm[4];                              // per-wave running max
    __shared__ float sd[4];                              // per-wave denom
    __shared__ float sacc[4][H];                         // per-wave acc (2 KB)
    if (threadIdx.x < B) qs_s[threadIdx.x] = qs[threadIdx.x];
    __syncthreads();

    const int lane = threadIdx.x & 63;
    const int wave = threadIdx.x >> 6;
    const int half = lane >> 5;
    const int hl   = lane & 31;
    const int hwid = wave * 2 + half;                    // 0..7
    const long r0  = (long)blockIdx.x * ROWS_PB;

    float4 w4 = ((const float4*)w)[hl];                  // w_h fragment

    const int sFirst = seg[r0];
    const int sLast  = seg[r0 + ROWS_PB - 1];

    if (sFirst == sLast) {
        // ---------------- FAST PATH: whole block in one segment ----------------
        const float qsv = qs_s[sFirst];
        float  m_run = -1e30f;
        float  d_run = 0.0f;
        float4 acc   = {0.0f, 0.0f, 0.0f, 0.0f};

        const int NIT = ROWS_PB / 32;                    // 8 iters, 4 consecutive rows/half-wave
        const float4* hp = (const float4*)(h + (r0 + (long)hwid * 4) * H) + hl;
        // software prefetch: loads of iter k+1 overlap the compute chain of iter k
        float4 h0 = ldnt(hp);                            // row base   (128 f = 32 float4)
        float4 h1 = ldnt(hp + 32);                       // row base+1
        float4 h2 = ldnt(hp + 64);                       // row base+2
        float4 h3 = ldnt(hp + 96);                       // row base+3

        for (int it = 0; it < NIT; ++it) {
            const bool more = (it + 1 < NIT);
            float4 n0, n1, n2, n3;
            if (more) {
                const float4* np = hp + 1024;            // +32 rows
                n0 = ldnt(np);
                n1 = ldnt(np + 32);
                n2 = ldnt(np + 64);
                n3 = ldnt(np + 96);
                hp = np;
            }

            float d0 = dot4(h0, w4), d1 = dot4(h1, w4);
            float d2 = dot4(h2, w4), d3 = dot4(h3, w4);

            // packed butterfly: 13 shuffles for 4 row-sums + broadcast (vs 20)
            float s0 = d0 + __shfl_xor(d0, 16, 32);
            float s1 = d1 + __shfl_xor(d1, 16, 32);
            float s2 = d2 + __shfl_xor(d2, 16, 32);
            float s3 = d3 + __shfl_xor(d3, 16, 32);
            float z01 = (hl & 16) ? s1 : s0;             // rows 0|1 in lane halves
            float z23 = (hl & 16) ? s3 : s2;             // rows 2|3
            float t01 = z01 + __shfl_xor(z01, 8, 32);
            float t23 = z23 + __shfl_xor(z23, 8, 32);
            float zz  = (hl & 8) ? t23 : t01;            // rows 0,2,1,3 in 8-lane groups
            zz += __shfl_xor(zz, 4, 32);
            zz += __shfl_xor(zz, 2, 32);
            zz += __shfl_xor(zz, 1, 32);
            float g0 = __shfl(zz,  0, 32) + qsv;
            float g1 = __shfl(zz, 16, 32) + qsv;
            float g2 = __shfl(zz,  8, 32) + qsv;
            float g3 = __shfl(zz, 24, 32) + qsv;
            g0 = (g0 >= 0.0f) ? g0 : NEG_SLOPE * g0;
            g1 = (g1 >= 0.0f) ? g1 : NEG_SLOPE * g1;
            g2 = (g2 >= 0.0f) ? g2 : NEG_SLOPE * g2;
            g3 = (g3 >= 0.0f) ? g3 : NEG_SLOPE * g3;

            // branchless batched online update: depth = 1 exp + fma tree
            float M  = fmaxf(fmaxf(m_run, g0), fmaxf(fmaxf(g1, g2), g3));
            float sc = __expf(m_run - M);                // == 1.0 when no new max; 0 on first iter
            float e0 = __expf(g0 - M);
            float e1 = __expf(g1 - M);
            float e2 = __expf(g2 - M);
            float e3 = __expf(g3 - M);
            acc.x = fmaf(acc.x, sc, fmaf(e0, h0.x, e1 * h1.x) + fmaf(e2, h2.x, e3 * h3.x));
            acc.y = fmaf(acc.y, sc, fmaf(e0, h0.y, e1 * h1.y) + fmaf(e2, h2.y, e3 * h3.y));
            acc.z = fmaf(acc.z, sc, fmaf(e0, h0.z, e1 * h1.z) + fmaf(e2, h2.z, e3 * h3.z));
            acc.w = fmaf(acc.w, sc, fmaf(e0, h0.w, e1 * h1.w) + fmaf(e2, h2.w, e3 * h3.w));
            d_run = fmaf(d_run, sc, (e0 + e1) + (e2 + e3));
            m_run = M;

            if (more) { h0 = n0; h1 = n1; h2 = n2; h3 = n3; }
        }
        // cross-half merge -> one partial per wave
        float m_o = __shfl_xor(m_run, 32);
        float d_o = __shfl_xor(d_run, 32);
        float4 a_o;
        a_o.x = __shfl_xor(acc.x, 32);
        a_o.y = __shfl_xor(acc.y, 32);
        a_o.z = __shfl_xor(acc.z, 32);
        a_o.w = __shfl_xor(acc.w, 32);
        float M  = fmaxf(m_run, m_o);
        float ss = __expf(m_run - M);
        float so = __expf(m_o  - M);
        float4 am;
        am.x = acc.x * ss + a_o.x * so;
        am.y = acc.y * ss + a_o.y * so;
        am.z = acc.z * ss + a_o.z * so;
        am.w = acc.w * ss + a_o.w * so;
        float Dm = d_run * ss + d_o * so;

        // cross-wave merge via LDS -> ONE partial per block (was 4)
        if (half == 0) ((float4*)&sacc[wave][0])[hl] = am;
        if (lane == 0) { sm[wave] = M; sd[wave] = Dm; }
        __syncthreads();
        if (wave == 0) {
            float Mb = fmaxf(fmaxf(sm[0], sm[1]), fmaxf(sm[2], sm[3]));
            float e0 = __expf(sm[0] - Mb);
            float e1 = __expf(sm[1] - Mb);
            float e2 = __expf(sm[2] - Mb);
            float e3 = __expf(sm[3] - Mb);
            // lane j owns columns 2j, 2j+1 (2-way LDS aliasing = free)
            int c = lane * 2;
            float2 a;
            a.x = fmaf(e0, sacc[0][c],     e1 * sacc[1][c])     + fmaf(e2, sacc[2][c],     e3 * sacc[3][c]);
            a.y = fmaf(e0, sacc[0][c + 1], e1 * sacc[1][c + 1]) + fmaf(e2, sacc[2][c + 1], e3 * sacc[3][c + 1]);
            float Db = fmaf(e0, sd[0], e1 * sd[1]) + fmaf(e2, sd[2], e3 * sd[3]);

            int slot = 0;
            if (lane == 0) slot = atomicAdd(counter + sFirst, 1);
            slot = min(__shfl(slot, 0), MAXP - 1);
            long pbase = (long)sFirst * MAXP + slot;
            ((float2*)(pacc + pbase * H))[lane] = a;
            if (lane == 0) { pm[pbase] = Mb; pd[pbase] = Db; }
        }
    } else {
        // ---------------- SLOW PATH: block crosses segment boundary ----------------
        int    cur   = -1;
        float  m_run = -1e30f;
        float  d_run = 0.0f;
        float4 acc   = {0.0f, 0.0f, 0.0f, 0.0f};

        for (int it = 0; it < ROWS_PB / 16; ++it) {      // 16 iters, 2 rows/half-wave
            long r1 = r0 + hwid + (long)it * 16;
            long r2 = r1 + 8;
            float4 ha = ldnt(((const float4*)(h + r1 * H)) + hl);
            float4 hb = ldnt(((const float4*)(h + r2 * H)) + hl);
            int s1 = seg[r1];
            int s2 = seg[r2];

            #pragma unroll
            for (int k = 0; k < 2; ++k) {
                float4 h4 = k ? hb : ha;
                int    s  = k ? s2 : s1;
                float d = dot4(h4, w4);
                #pragma unroll
                for (int off = 1; off < 32; off <<= 1) d += __shfl_xor(d, off, 32);
                float g = d + qs_s[s];
                g = (g >= 0.0f) ? g : NEG_SLOPE * g;

                if (s != cur) {                          // half-wave-uniform branch
                    if (cur >= 0) {
                        int slot = 0;
                        if (hl == 0) slot = atomicAdd(counter + cur, 1);
                        slot = min(__shfl(slot, 0, 32), MAXP - 1);
                        long pbase = (long)cur * MAXP + slot;
                        ((float4*)(pacc + pbase * H))[hl] = acc;
                        if (hl == 0) { pm[pbase] = m_run; pd[pbase] = d_run; }
                    }
                    cur = s;
                    m_run = -1e30f;
                    d_run = 0.0f;
                    acc = make_float4(0.0f, 0.0f, 0.0f, 0.0f);
                }
                if (g <= m_run) {
                    float e = __expf(g - m_run);
                    acc.x += e * h4.x;
                    acc.y += e * h4.y;
                    acc.z += e * h4.z;
                    acc.w += e * h4.w;
                    d_run += e;
                } else {
                    float sc = __expf(m_run - g);
                    acc.x = acc.x * sc + h4.x;
                    acc.y = acc.y * sc + h4.y;
                    acc.z = acc.z * sc + h4.z;
                    acc.w = acc.w * sc + h4.w;
                    d_run = d_run * sc + 1.0f;
                    m_run = g;
                }
            }
        }
        if (cur >= 0) {
            int slot = 0;
            if (hl == 0) slot = atomicAdd(counter + cur, 1);
            slot = min(__shfl(slot, 0, 32), MAXP - 1);
            long pbase = (long)cur * MAXP + slot;
            ((float4*)(pacc + pbase * H))[hl] = acc;
            if (hl == 0) { pm[pbase] = m_run; pd[pbase] = d_run; }
        }
    }
}

// ---------- merge partials per segment (parallelized), divide, write out ----------
__global__ __launch_bounds__(128) void merge_kernel(const int* __restrict__ counter,
                                                    const float* __restrict__ pm,
                                                    const float* __restrict__ pd,
                                                    const float* __restrict__ pacc,
                                                    float* __restrict__ out) {
    const int s = blockIdx.x;
    const int t = threadIdx.x;                           // 0..127 = H column
    const int c = min(counter[s], MAXP);
    const long sb = (long)s * MAXP;

    __shared__ float red[2];
    __shared__ float scv[MAXP];

    // phase 1: segment max over partials
    float lm = -1e30f;
    for (int j = t; j < c; j += 128) lm = fmaxf(lm, pm[sb + j]);
    #pragma unroll
    for (int off = 1; off < 64; off <<= 1) lm = fmaxf(lm, __shfl_xor(lm, off));
    if ((t & 63) == 0) red[t >> 6] = lm;
    __syncthreads();
    float M = fmaxf(red[0], red[1]);
    __syncthreads();

    // phase 2a: scales to LDS + denom reduce
    float ld = 0.0f;
    for (int j = t; j < c; j += 128) {
        float sc = __expf(pm[sb + j] - M);
        scv[j] = sc;
        ld += pd[sb + j] * sc;
    }
    #pragma unroll
    for (int off = 1; off < 64; off <<= 1) ld += __shfl_xor(ld, off);
    if ((t & 63) == 0) red[t >> 6] = ld;
    __syncthreads();
    float D = red[0] + red[1];

    // phase 2b: weighted accumulation (coalesced)
    float a = 0.0f;
    #pragma unroll 4
    for (int j = 0; j < c; ++j) a += pacc[(sb + j) * H + t] * scv[j];

    out[s * H + t] = (c > 0) ? a / fmaxf(D, 1e-20f) : 0.0f;
}

extern "C" void kernel_launch(void* const* d_in, const int* in_sizes, int n_in,
                              void* d_out, int out_size, void* d_ws, size_t ws_size,
                              hipStream_t stream) {
    const float* h   = (const float*)d_in[0];   // (N, H)
    const float* aq  = (const float*)d_in[1];   // (B, H)
    const float* w   = (const float*)d_in[2];   // (2H,)
    const int*   seg = (const int*)d_in[3];     // (N,) sorted
    float* out = (float*)d_out;                 // (B, H)

    // ws layout (floats): qs[B] | counter[B] (int) | pm[B*MAXP] | pd[B*MAXP] | pacc[B*MAXP*H]
    float* ws      = (float*)d_ws;
    float* qs      = ws;
    int*   counter = (int*)(ws + B);
    float* pm      = ws + 2 * B;
    float* pd      = ws + 2 * B + B * MAXP;
    float* pacc    = ws + 2 * B + 2 * B * MAXP;   // 16B-aligned

    qs_init_kernel<<<16, 256, 0, stream>>>(aq, w, qs, counter);
    main_kernel<<<GRID_MAIN, 256, 0, stream>>>(h, seg, w, qs, counter, pm, pd, pacc);
    merge_kernel<<<B, 128, 0, stream>>>(counter, pm, pd, pacc, out);
}